// Round 6
// baseline (4858.614 us; speedup 1.0000x reference)
//
#include <hip/hip_runtime.h>

// ConvLSTM on MI355X — round 6: split each batch's recurrence across 2 CUs by
// h-channel half. Block p computes gate rows for h-ch 32p..32p+31 only:
//   * weights halve to 72KB -> LDS-resident (imm-offset ds_read_b128, zero
//     per-step weight VALU/VMEM — the r1/r5 weight-access tax is gone),
//   * MFMA and gate-transcendental work per CU halve,
//   * per-step 8KB h-slab exchange through d_ws with agent-scope atomics
//     (2-slot ring; blocks provably within 1 step of each other),
//   * output dot splits by h -> direct stores, no atomics/epilogue.
// ws guard -> proven round-1 fallback.

#define Bb 32
#define Tt 128
#define Cc 32
#define Ss 256
#define Hh 64
#define ZST 104  // Z row stride in u16 (208 B, 16B-aligned rows)

typedef __bf16 bf16x8 __attribute__((ext_vector_type(8)));
typedef short  short8 __attribute__((ext_vector_type(8)));
typedef float  f32x4  __attribute__((ext_vector_type(4)));
typedef unsigned short u16;
typedef unsigned int   u32;
typedef unsigned long long u64;

__device__ __forceinline__ u16 f2bf(float f) {
    u32 u = __float_as_uint(f);
    u = (u + 0x7FFFu + ((u >> 16) & 1u)) >> 16;  // RNE
    return (u16)u;
}
__device__ __forceinline__ float fsig(float x) {
    float e = __expf(-x);
    return __builtin_amdgcn_rcpf(1.0f + e);
}
__device__ __forceinline__ float ftanh_(float x) {
    float e = __expf(2.0f * x);
    return 1.0f - 2.0f * __builtin_amdgcn_rcpf(e + 1.0f);
}
__device__ __forceinline__ u32 cvtpk(float lo, float hi) {
    u32 d;
    asm("v_cvt_pk_bf16_f32 %0, %1, %2" : "=v"(d) : "v"(lo), "v"(hi));
    return d;
}

// ---------------- transpose: x (B,T,C,S) f32 -> xT (B,S,T*C) bf16 ----------------
__global__ __launch_bounds__(256) void xpose_kernel(const float* __restrict__ x,
                                                    u16* __restrict__ xT) {
    __shared__ u16 tile[64][130];
    const int tc0 = blockIdx.x * 128;
    const int s0  = blockIdx.y * 64;
    const int b   = blockIdx.z;
    const int tid = threadIdx.x;
    const float* xb = x + (size_t)b * (Tt * Cc * Ss);
#pragma unroll
    for (int i = 0; i < 32; ++i) {
        const int tcr = (tid >> 6) + 4 * i;
        const int sr  = tid & 63;
        tile[sr][tcr] = f2bf(xb[(size_t)(tc0 + tcr) * Ss + s0 + sr]);
    }
    __syncthreads();
    u32* xTo = (u32*)(xT + (size_t)b * (Ss * Tt * Cc));
#pragma unroll
    for (int j = 0; j < 16; ++j) {
        const int sw = (tid >> 6) + 4 * j;
        const int tw = (tid & 63) * 2;
        xTo[(((size_t)(s0 + sw)) * (Tt * Cc) + tc0 + tw) >> 1] = *(const u32*)&tile[sw][tw];
    }
}

// ---------------- weight prep: Wc f32 -> wpre[ht][f=(g*9+k*3+ks)][lane][8] bf16 ----------------
__global__ __launch_bounds__(256) void wprep_kernel(const float* __restrict__ Wc,
                                                    u16* __restrict__ wpre) {
    const int ht  = blockIdx.x;   // 0..3
    const int tid = threadIdx.x;
#pragma unroll
    for (int it = 0; it < 9; ++it) {
        const int idx  = it * 256 + tid;      // 0..2303
        const int f    = idx >> 6;            // 0..35
        const int lane = idx & 63;
        const int g  = f / 9;
        const int k  = (f % 9) / 3;
        const int ks = f % 3;
        const int l15 = lane & 15;
        const int q   = lane >> 4;
        const int gc  = 64 * g + 16 * ht + l15;
        u16 tmp[8];
#pragma unroll
        for (int j = 0; j < 8; ++j)
            tmp[j] = f2bf(Wc[gc * 288 + (32 * ks + 8 * q + j) * 3 + k]);
        *(uint4*)(wpre + ((size_t)(ht * 36 + f) * 64 + lane) * 8) = *(const uint4*)tmp;
    }
}

// ---------------- recurrent kernel: 2 blocks per batch (h-channel split) ----------------
__global__ __launch_bounds__(512) void convlstm6_kernel(
    const float* __restrict__ bc, const float* __restrict__ Wl,
    const float* __restrict__ bl, const u16* __restrict__ xT,
    const u16* __restrict__ wpre, u64* __restrict__ halo,
    u32* __restrict__ flags, float* __restrict__ out) {

    __shared__ u16  wlds[36864];          // 72 KB: this block's weight half
    __shared__ u16  zbuf[2][130][ZST];    // rows t=-1..128; cols 0..31 x, 32..95 h (all 64)
    __shared__ float red[8][16];

    const int p    = blockIdx.x;   // h-half
    const int b    = blockIdx.y;
    const int tid  = threadIdx.x;
    const int w    = tid >> 6;
    const int lane = tid & 63;
    const int l15  = lane & 15;
    const int q    = lane >> 4;
    const int th   = w >> 1;       // t-quarter 0..3 (32 t each)
    const int ht2  = w & 1;        // local 16-row h tile

    {   // zero both Z buffers (x/h halos + h(-1) = 0)
        u32* z32 = (u32*)&zbuf[0][0][0];
        for (int i = tid; i < (2 * 130 * ZST) / 2; i += 512) z32[i] = 0;
    }
    {   // stage this block's weight half (ht slices 2p, 2p+1) into LDS
        const uint4* wsrc = (const uint4*)(wpre + (size_t)(2 * p) * 18432);
        uint4* wdst = (uint4*)wlds;
#pragma unroll
        for (int i = 0; i < 9; ++i) wdst[tid + 512 * i] = wsrc[tid + 512 * i];
    }

    f32x4 bcv[4];
#pragma unroll
    for (int g = 0; g < 4; ++g)
        bcv[g] = *(const f32x4*)&bc[64 * g + 32 * p + 16 * ht2 + 4 * q];
    float wlv[2];
#pragma unroll
    for (int nj = 0; nj < 2; ++nj) wlv[nj] = Wl[32 * th + 16 * nj + l15];
    const float bl0 = bl[0];

    float cst[8];
#pragma unroll
    for (int i = 0; i < 8; ++i) cst[i] = 0.0f;

    // x staging: thread -> one uint4: row t = tid>>2, c0 = (tid&3)*8
    const int xr = tid >> 2;
    const int xc = (tid & 3) * 8;
    const u16* xTb = xT + (size_t)b * (Ss * Tt * Cc);

    // halo/flag pointers (2-slot ring per (b, publisher))
    u64* haloP = halo + (size_t)(b * 2 + p) * 2 * 1024;
    const u64* haloC = halo + (size_t)(b * 2 + (1 - p)) * 2 * 1024;
    u32* flagP = flags + (b * 2 + p) * 2;
    u32* flagC = flags + (b * 2 + (1 - p)) * 2;

    // prime x(0) into buffer 1 (step s reads zbuf[(s+1)&1])
    {
        uint4 xv0 = *(const uint4*)(xTb + xr * 32 + xc);
        __syncthreads();  // zeroing + wlds staged
        *(uint4*)&zbuf[1][1 + xr][xc] = xv0;
        __syncthreads();
    }

    float* outb = out + (size_t)b * (Ss * Hh) + 32 * p;
    const u16* wl0 = wlds + ht2 * 18432 + lane * 8;

    for (int s = 0; s < Ss; ++s) {
        uint4 xv;
        const bool havex = (s + 1) < Ss;
        if (havex) xv = *(const uint4*)(xTb + (size_t)(s + 1) * (Tt * Cc) + xr * 32 + xc);

        // emit output for step s-1 (this block's 32 h-channels)
        if (tid < 32 && s > 0) {
            const int h2 = tid >> 4, hh = tid & 15;
            float v = red[h2][hh] + red[2 + h2][hh] + red[4 + h2][hh] + red[6 + h2][hh] + bl0;
            outb[(size_t)(s - 1) * Hh + 16 * h2 + hh] = fsig(v);
        }
        __syncthreads();  // barrier A: red consumed before rewrite

        const u16 (*zb)[ZST] = zbuf[(s + 1) & 1];  // [x(s); h(s-1) full]
        u16 (*zn)[ZST] = zbuf[s & 1];              // gets h(s) own half + ingested half + x(s+1)

        // ---- conv: K = 96ch x 3 taps, both nj groups fused (weights read once) ----
        f32x4 acc[2][4];
#pragma unroll
        for (int nj = 0; nj < 2; ++nj)
#pragma unroll
            for (int g = 0; g < 4; ++g) acc[nj][g] = bcv[g];

#pragma unroll
        for (int k = 0; k < 3; ++k)
#pragma unroll
            for (int ks = 0; ks < 3; ++ks) {
                bf16x8 wf0 = *(const bf16x8*)(wl0 + (0 * 9 + k * 3 + ks) * 512);
                bf16x8 wf1 = *(const bf16x8*)(wl0 + (1 * 9 + k * 3 + ks) * 512);
                bf16x8 wf2 = *(const bf16x8*)(wl0 + (2 * 9 + k * 3 + ks) * 512);
                bf16x8 wf3 = *(const bf16x8*)(wl0 + (3 * 9 + k * 3 + ks) * 512);
#pragma unroll
                for (int nj = 0; nj < 2; ++nj) {
                    bf16x8 bfr = *(const bf16x8*)&zb[32 * th + 16 * nj + l15 + k][32 * ks + 8 * q];
                    acc[nj][0] = __builtin_amdgcn_mfma_f32_16x16x32_bf16(wf0, bfr, acc[nj][0], 0, 0, 0);
                    acc[nj][1] = __builtin_amdgcn_mfma_f32_16x16x32_bf16(wf1, bfr, acc[nj][1], 0, 0, 0);
                    acc[nj][2] = __builtin_amdgcn_mfma_f32_16x16x32_bf16(wf2, bfr, acc[nj][2], 0, 0, 0);
                    acc[nj][3] = __builtin_amdgcn_mfma_f32_16x16x32_bf16(wf3, bfr, acc[nj][3], 0, 0, 0);
                }
            }

        // ---- gates, h write, publish ----
        float partial[4] = {0.f, 0.f, 0.f, 0.f};
#pragma unroll
        for (int nj = 0; nj < 2; ++nj) {
            float hv[4];
#pragma unroll
            for (int r = 0; r < 4; ++r) {
                const float ig = fsig(acc[nj][0][r]);
                const float fg = fsig(acc[nj][1][r]);
                const float og = fsig(acc[nj][2][r]);
                const float gg = ftanh_(acc[nj][3][r]);
                const float cv = fg * cst[nj * 4 + r] + ig * gg;
                cst[nj * 4 + r] = cv;
                hv[r] = og * ftanh_(cv);
                partial[r] += hv[r] * wlv[nj];
            }
            const u32 hx = cvtpk(hv[0], hv[1]);
            const u32 hy = cvtpk(hv[2], hv[3]);
            const int t = 32 * th + 16 * nj + l15;
            uint2 hw; hw.x = hx; hw.y = hy;
            *(uint2*)&zn[1 + t][32 + 32 * p + 16 * ht2 + 4 * q] = hw;
            const u64 pv = (u64)hx | ((u64)hy << 32);
            __hip_atomic_store(&haloP[(size_t)(s & 1) * 1024 + t * 8 + 4 * ht2 + q], pv,
                               __ATOMIC_RELAXED, __HIP_MEMORY_SCOPE_AGENT);
        }
        if (lane == 0)  // release waits this wave's halo stores (vmcnt drain)
            __hip_atomic_fetch_add(&flagP[s & 1], 1u, __ATOMIC_RELEASE, __HIP_MEMORY_SCOPE_AGENT);

        // x(s+1) into zn
        if (havex) *(uint4*)&zn[1 + xr][xc] = xv;

        // per-wave output partial reduce over the 16 t-lanes
#pragma unroll
        for (int r = 0; r < 4; ++r) {
#pragma unroll
            for (int offl = 1; offl <= 8; offl <<= 1)
                partial[r] += __shfl_xor(partial[r], offl, 64);
        }
        if (l15 == 0) {
#pragma unroll
            for (int r = 0; r < 4; ++r) red[w][4 * q + r] = partial[r];
        }

        // ---- ingest neighbor's h(s) half into zn ----
        if (s + 1 < Ss) {
            if (lane == 0) {
                const u32 tgt = 8u * ((u32)(s >> 1) + 1u);
                while (__hip_atomic_load(&flagC[s & 1], __ATOMIC_ACQUIRE,
                                         __HIP_MEMORY_SCOPE_AGENT) < tgt) {}
            }
            const u64* hsrc = haloC + (size_t)(s & 1) * 1024;
#pragma unroll
            for (int ii = 0; ii < 2; ++ii) {
                const int j = tid + 512 * ii;     // 0..1023: t = j>>3, ch4 = (j&7)*4
                const u64 v = __hip_atomic_load(&hsrc[j], __ATOMIC_RELAXED,
                                                __HIP_MEMORY_SCOPE_AGENT);
                uint2 vw; vw.x = (u32)v; vw.y = (u32)(v >> 32);
                *(uint2*)&zn[1 + (j >> 3)][32 + 32 * (1 - p) + 4 * (j & 7)] = vw;
            }
        }
        __syncthreads();  // barrier B: h(s) both halves + x(s+1) + red visible
    }

    if (tid < 32) {  // final output, s = Ss-1
        const int h2 = tid >> 4, hh = tid & 15;
        float v = red[h2][hh] + red[2 + h2][hh] + red[4 + h2][hh] + red[6 + h2][hh] + bl0;
        outb[(size_t)(Ss - 1) * Hh + 16 * h2 + hh] = fsig(v);
    }
}

// ---------------- round-1 fallback (proven; used if ws too small) ----------------
__global__ __launch_bounds__(512, 2) void convlstm_kernel(
    const float* __restrict__ Wc, const float* __restrict__ bc,
    const float* __restrict__ Wl, const float* __restrict__ bl,
    const u16* __restrict__ xT, float* __restrict__ out) {

    __shared__ u16  zbuf[2][130][ZST];
    __shared__ float red[8][16];
    __shared__ float bcl[256];

    const int b    = blockIdx.x;
    const int tid  = threadIdx.x;
    const int w    = tid >> 6;
    const int lane = tid & 63;
    const int l15  = lane & 15;
    const int q    = lane >> 4;
    const int ht   = w >> 1;
    const int th   = w & 1;

    {
        u32* z32 = (u32*)&zbuf[0][0][0];
        for (int i = tid; i < (2 * 130 * ZST) / 2; i += 512) z32[i] = 0;
    }
    if (tid < 256) bcl[tid] = bc[tid];

    bf16x8 afr[4][3][3];
#pragma unroll
    for (int g = 0; g < 4; ++g)
#pragma unroll
        for (int k = 0; k < 3; ++k)
#pragma unroll
            for (int ks = 0; ks < 3; ++ks) {
                const int gc = 64 * g + 16 * ht + l15;
                short8 t;
#pragma unroll
                for (int j = 0; j < 8; ++j)
                    t[j] = (short)f2bf(Wc[gc * 288 + (32 * ks + 8 * q + j) * 3 + k]);
                afr[g][k][ks] = __builtin_bit_cast(bf16x8, t);
            }

    float wlv[4];
#pragma unroll
    for (int nj = 0; nj < 4; ++nj) wlv[nj] = Wl[64 * th + 16 * nj + l15];
    const float bl0 = bl[0];

    float cst[16];
#pragma unroll
    for (int i = 0; i < 16; ++i) cst[i] = 0.0f;

    const int xt = tid >> 2;
    const int xc = (tid & 3) * 8;
    const u16* xTb = xT + (size_t)b * (Ss * Tt * Cc);

    {
        uint4 xv0 = *(const uint4*)(xTb + xt * 32 + xc);
        __syncthreads();
        *(uint4*)&zbuf[0][1 + xt][xc] = xv0;
        __syncthreads();
    }

    float* outb = out + (size_t)b * (Ss * Hh);
    int pp = 0;

    for (int s = 0; s < Ss; ++s) {
        uint4 xv;
        const bool havex = (s + 1) < Ss;
        if (havex) xv = *(const uint4*)(xTb + (size_t)(s + 1) * (Tt * Cc) + xt * 32 + xc);

        if (tid < 64 && s > 0) {
            float v = red[(tid >> 4) * 2][tid & 15] + red[(tid >> 4) * 2 + 1][tid & 15] + bl0;
            outb[(size_t)(s - 1) * Hh + tid] = fsig(v);
        }
        __syncthreads();

        const u16 (*zb)[ZST] = zbuf[pp];
        u16 (*zn)[ZST] = zbuf[pp ^ 1];

        float partial[4] = {0.f, 0.f, 0.f, 0.f};

#pragma unroll
        for (int half = 0; half < 2; ++half) {
            f32x4 acc[4][2];
#pragma unroll
            for (int g = 0; g < 4; ++g) {
                acc[g][0] = (f32x4){0.f, 0.f, 0.f, 0.f};
                acc[g][1] = (f32x4){0.f, 0.f, 0.f, 0.f};
            }
#pragma unroll
            for (int njl = 0; njl < 2; ++njl) {
                const int nj = half * 2 + njl;
                const int tb = 64 * th + 16 * nj + l15;
#pragma unroll
                for (int k = 0; k < 3; ++k)
#pragma unroll
                    for (int ks = 0; ks < 3; ++ks) {
                        bf16x8 bfr = *(const bf16x8*)&zb[tb + k][32 * ks + 8 * q];
                        acc[0][njl] = __builtin_amdgcn_mfma_f32_16x16x32_bf16(afr[0][k][ks], bfr, acc[0][njl], 0, 0, 0);
                        acc[1][njl] = __builtin_amdgcn_mfma_f32_16x16x32_bf16(afr[1][k][ks], bfr, acc[1][njl], 0, 0, 0);
                        acc[2][njl] = __builtin_amdgcn_mfma_f32_16x16x32_bf16(afr[2][k][ks], bfr, acc[2][njl], 0, 0, 0);
                        acc[3][njl] = __builtin_amdgcn_mfma_f32_16x16x32_bf16(afr[3][k][ks], bfr, acc[3][njl], 0, 0, 0);
                    }
            }

#pragma unroll
            for (int njl = 0; njl < 2; ++njl) {
                const int nj = half * 2 + njl;
                u16 hp[4];
#pragma unroll
                for (int r = 0; r < 4; ++r) {
                    const int hl = 4 * q + r;
                    const float ig = fsig(acc[0][njl][r] + bcl[0   + 16 * ht + hl]);
                    const float fg = fsig(acc[1][njl][r] + bcl[64  + 16 * ht + hl]);
                    const float og = fsig(acc[2][njl][r] + bcl[128 + 16 * ht + hl]);
                    const float gg = ftanh_(acc[3][njl][r] + bcl[192 + 16 * ht + hl]);
                    const float cv = fg * cst[nj * 4 + r] + ig * gg;
                    cst[nj * 4 + r] = cv;
                    const float hv = og * ftanh_(cv);
                    partial[r] += hv * wlv[nj];
                    hp[r] = f2bf(hv);
                }
                uint2 hw;
                hw.x = (u32)hp[0] | ((u32)hp[1] << 16);
                hw.y = (u32)hp[2] | ((u32)hp[3] << 16);
                *(uint2*)&zn[1 + 64 * th + 16 * nj + l15][32 + 16 * ht + 4 * q] = hw;
            }
        }

        if (havex) *(uint4*)&zn[1 + xt][xc] = xv;

#pragma unroll
        for (int r = 0; r < 4; ++r) {
#pragma unroll
            for (int offl = 1; offl <= 8; offl <<= 1)
                partial[r] += __shfl_xor(partial[r], offl, 64);
        }
        if (l15 == 0) {
#pragma unroll
            for (int r = 0; r < 4; ++r) red[w][4 * q + r] = partial[r];
        }
        __syncthreads();
        pp ^= 1;
    }

    if (tid < 64) {
        float v = red[(tid >> 4) * 2][tid & 15] + red[(tid >> 4) * 2 + 1][tid & 15] + bl0;
        outb[(size_t)(Ss - 1) * Hh + tid] = fsig(v);
    }
}

extern "C" void kernel_launch(void* const* d_in, const int* in_sizes, int n_in,
                              void* d_out, int out_size, void* d_ws, size_t ws_size,
                              hipStream_t stream) {
    const float* x  = (const float*)d_in[0];
    const float* Wc = (const float*)d_in[1];
    const float* bc = (const float*)d_in[2];
    const float* Wl = (const float*)d_in[3];
    const float* bl = (const float*)d_in[4];
    float* out = (float*)d_out;

    u16* xT = (u16*)d_ws;
    const size_t XT_BYTES   = (size_t)Bb * Ss * Tt * Cc * 2;  // 64 MiB
    const size_t WP_BYTES   = (size_t)4 * 36 * 64 * 8 * 2;    // 144 KiB
    const size_t HALO_BYTES = (size_t)Bb * 2 * 2 * 1024 * 8;  // 2 MiB
    const size_t FLAG_BYTES = (size_t)Bb * 2 * 2 * 4;         // 512 B

    dim3 tgrid(Tt * Cc / 128, Ss / 64, Bb);
    xpose_kernel<<<tgrid, 256, 0, stream>>>(x, xT);

    if (ws_size >= XT_BYTES + WP_BYTES + HALO_BYTES + FLAG_BYTES) {
        u16* wpre  = (u16*)((char*)d_ws + XT_BYTES);
        u64* halo  = (u64*)((char*)d_ws + XT_BYTES + WP_BYTES);
        u32* flags = (u32*)((char*)d_ws + XT_BYTES + WP_BYTES + HALO_BYTES);
        wprep_kernel<<<4, 256, 0, stream>>>(Wc, wpre);
        hipMemsetAsync(flags, 0, FLAG_BYTES, stream);
        convlstm6_kernel<<<dim3(2, Bb), 512, 0, stream>>>(bc, Wl, bl, xT, wpre, halo, flags, out);
    } else {
        convlstm_kernel<<<Bb, 512, 0, stream>>>(Wc, bc, Wl, bl, xT, out);
    }
}

// Round 7
// 1482.152 us; speedup vs baseline: 3.2781x; 3.2781x over previous
//
#include <hip/hip_runtime.h>

// ConvLSTM on MI355X — round 7.
// Theory (from r1/r3/r5/r6 counter evidence): the backend caps VGPRs at 128
// whenever LDS < 80KB (2 blocks/CU achievable -> 16 waves/CU budget), and
// launch_bounds/waves_per_eu don't override it. With only 32 blocks we run
// 1 block/CU anyway, so padding LDS past 80KB is free and lifts the budget to
// 256 -> the 144-VGPR weight set stays resident WITHOUT pins (no pressure ->
// no remat, no spill). Kernel body = round-3 single-barrier pipelined
// structure (bit-correct, absmax 0.0039), no asm pins.

#define Bb 32
#define Tt 128
#define Cc 32
#define Ss 256
#define Hh 64
#define ZST 104  // Z row stride in u16 (208 B)

typedef __bf16 bf16x8 __attribute__((ext_vector_type(8)));
typedef short  short8 __attribute__((ext_vector_type(8)));
typedef float  f32x4  __attribute__((ext_vector_type(4)));
typedef unsigned short u16;
typedef unsigned int   u32;

__device__ __forceinline__ u16 f2bf(float f) {
    u32 u = __float_as_uint(f);
    u = (u + 0x7FFFu + ((u >> 16) & 1u)) >> 16;  // RNE
    return (u16)u;
}
__device__ __forceinline__ float fsig(float x) {
    float e = __expf(-x);
    return __builtin_amdgcn_rcpf(1.0f + e);
}
__device__ __forceinline__ float ftanh_(float x) {
    float e = __expf(2.0f * x);
    return 1.0f - 2.0f * __builtin_amdgcn_rcpf(e + 1.0f);
}
__device__ __forceinline__ u32 cvtpk(float lo, float hi) {
    u32 d;
    asm("v_cvt_pk_bf16_f32 %0, %1, %2" : "=v"(d) : "v"(lo), "v"(hi));
    return d;
}

// ---------------- transpose: x (B,T,C,S) f32 -> xT (B,S,T*C) bf16 ----------------
__global__ __launch_bounds__(256) void xpose_kernel(const float* __restrict__ x,
                                                    u16* __restrict__ xT) {
    __shared__ u16 tile[64][130];
    const int tc0 = blockIdx.x * 128;
    const int s0  = blockIdx.y * 64;
    const int b   = blockIdx.z;
    const int tid = threadIdx.x;
    const float* xb = x + (size_t)b * (Tt * Cc * Ss);
#pragma unroll
    for (int i = 0; i < 32; ++i) {
        const int tcr = (tid >> 6) + 4 * i;
        const int sr  = tid & 63;
        tile[sr][tcr] = f2bf(xb[(size_t)(tc0 + tcr) * Ss + s0 + sr]);
    }
    __syncthreads();
    u32* xTo = (u32*)(xT + (size_t)b * (Ss * Tt * Cc));
#pragma unroll
    for (int j = 0; j < 16; ++j) {
        const int sw = (tid >> 6) + 4 * j;
        const int tw = (tid & 63) * 2;
        xTo[(((size_t)(s0 + sw)) * (Tt * Cc) + tc0 + tw) >> 1] = *(const u32*)&tile[sw][tw];
    }
}

// ---------------- recurrent kernel: one block per batch ----------------
__global__ __launch_bounds__(512) void convlstm7_kernel(
    const float* __restrict__ Wc, const float* __restrict__ bc,
    const float* __restrict__ Wl, const float* __restrict__ bl,
    const u16* __restrict__ xT, float* __restrict__ out) {

    // Z: rows 0..129 = t -1..128 (halo rows stay zero), cols 0..31 x, 32..95 h
    __shared__ u16  zbuf[2][130][ZST];
    __shared__ float red[2][8][16];
    // Occupancy shaping: push block LDS past 80KB so the backend budgets
    // registers for 1 block/CU (8 waves -> 256 VGPRs/wave). Only 32 blocks
    // exist, so 1 block/CU is reality regardless — this wastes nothing.
    __shared__ u16  zpad[14000];

    const int b    = blockIdx.x;
    const int tid  = threadIdx.x;
    const int w    = tid >> 6;     // wave 0..7
    const int lane = tid & 63;
    const int l15  = lane & 15;
    const int q    = lane >> 4;
    const int ht   = w >> 1;       // 16 h-rows tile
    const int th   = w & 1;        // t-half

    if (blockIdx.x == 0xFFFFFFFFu) zpad[tid] = 0;  // keep zpad allocated (never true)

    {   // zero both Z buffers (halos + h(-1) = 0)
        u32* z32 = (u32*)&zbuf[0][0][0];
        for (int i = tid; i < (2 * 130 * ZST) / 2; i += 512) z32[i] = 0;
    }

    // weight fragments, loop-invariant: afr[gate][tap][ks]; k-slot j -> ch 32*ks+8*q+j
    bf16x8 afr[4][3][3];
#pragma unroll
    for (int g = 0; g < 4; ++g)
#pragma unroll
        for (int k = 0; k < 3; ++k)
#pragma unroll
            for (int ks = 0; ks < 3; ++ks) {
                const int gc = 64 * g + 16 * ht + l15;
                short8 t;
#pragma unroll
                for (int j = 0; j < 8; ++j)
                    t[j] = (short)f2bf(Wc[gc * 288 + (32 * ks + 8 * q + j) * 3 + k]);
                afr[g][k][ks] = __builtin_bit_cast(bf16x8, t);
            }

    // bias (acc-init) and Wl
    f32x4 bcv[4];
#pragma unroll
    for (int g = 0; g < 4; ++g) bcv[g] = *(const f32x4*)&bc[64 * g + 16 * ht + 4 * q];
    float wlv[4];
#pragma unroll
    for (int nj = 0; nj < 4; ++nj) wlv[nj] = Wl[64 * th + 16 * nj + l15];
    const float bl0 = bl[0];

    float cst[16];
#pragma unroll
    for (int i = 0; i < 16; ++i) cst[i] = 0.0f;

    // x staging: thread -> (t = tid>>2, c0 = (tid&3)*8)
    const int xt = tid >> 2;
    const int xc = (tid & 3) * 8;
    const u16* xTb = xT + (size_t)b * (Ss * Tt * Cc);

    // prime x(0) into buffer 1 (step s reads zbuf[(s+1)&1])
    {
        uint4 xv0 = *(const uint4*)(xTb + xt * 32 + xc);
        __syncthreads();  // zeroing complete
        *(uint4*)&zbuf[1][1 + xt][xc] = xv0;
        __syncthreads();  // x(0) visible
    }

    float* outb = out + (size_t)b * (Ss * Hh);

    for (int s = 0; s < Ss; ++s) {
        // prefetch x(s+1)
        uint4 xv;
        const bool havex = (s + 1) < Ss;
        if (havex) xv = *(const uint4*)(xTb + (size_t)(s + 1) * (Tt * Cc) + xt * 32 + xc);

        // emit output for step s-1 (red double-buffered)
        if (tid < 64 && s > 0) {
            const int ps = (s - 1) & 1;
            float v = red[ps][(tid >> 4) * 2][tid & 15] + red[ps][(tid >> 4) * 2 + 1][tid & 15] + bl0;
            outb[(size_t)(s - 1) * Hh + tid] = fsig(v);
        }

        const u16 (*zb)[ZST] = zbuf[(s & 1) ^ 1];  // [x(s); h(s-1)]
        u16 (*zn)[ZST] = zbuf[s & 1];              // gets h(s), x(s+1)

        float partial[4] = {0.f, 0.f, 0.f, 0.f};
        f32x4 acc[2][4];

#pragma unroll
        for (int c = 0; c < 5; ++c) {
            if (c < 4) {
                // acc(c) init = bias; MFMAs for chunk nj = c (K = 96ch x 3 taps)
#pragma unroll
                for (int g = 0; g < 4; ++g) acc[c & 1][g] = bcv[g];
                const int tb = 64 * th + 16 * c + l15;
#pragma unroll
                for (int k = 0; k < 3; ++k)
#pragma unroll
                    for (int ks = 0; ks < 3; ++ks) {
                        bf16x8 bfr = *(const bf16x8*)&zb[tb + k][32 * ks + 8 * q];
                        acc[c & 1][0] = __builtin_amdgcn_mfma_f32_16x16x32_bf16(afr[0][k][ks], bfr, acc[c & 1][0], 0, 0, 0);
                        acc[c & 1][1] = __builtin_amdgcn_mfma_f32_16x16x32_bf16(afr[1][k][ks], bfr, acc[c & 1][1], 0, 0, 0);
                        acc[c & 1][2] = __builtin_amdgcn_mfma_f32_16x16x32_bf16(afr[2][k][ks], bfr, acc[c & 1][2], 0, 0, 0);
                        acc[c & 1][3] = __builtin_amdgcn_mfma_f32_16x16x32_bf16(afr[3][k][ks], bfr, acc[c & 1][3], 0, 0, 0);
                    }
            }
            if (c > 0) {  // gates for chunk c-1, in the MFMA shadow of chunk c
                const int nj = c - 1;
                float hv[4];
#pragma unroll
                for (int r = 0; r < 4; ++r) {
                    const float ig = fsig(acc[nj & 1][0][r]);
                    const float fg = fsig(acc[nj & 1][1][r]);
                    const float og = fsig(acc[nj & 1][2][r]);
                    const float gg = ftanh_(acc[nj & 1][3][r]);
                    const float cv = fg * cst[nj * 4 + r] + ig * gg;
                    cst[nj * 4 + r] = cv;
                    hv[r] = og * ftanh_(cv);
                    partial[r] += hv[r] * wlv[nj];
                }
                uint2 hw;
                hw.x = cvtpk(hv[0], hv[1]);
                hw.y = cvtpk(hv[2], hv[3]);
                // h channel = 16*ht + 4*q + r -> Z col 32 + that
                *(uint2*)&zn[1 + 64 * th + 16 * nj + l15][32 + 16 * ht + 4 * q] = hw;
            }
        }

        // write prefetched x(s+1)
        if (havex) *(uint4*)&zn[1 + xt][xc] = xv;

        // reduce output partials over the 16 t-lanes of each quarter
#pragma unroll
        for (int r = 0; r < 4; ++r) {
#pragma unroll
            for (int offl = 1; offl <= 8; offl <<= 1)
                partial[r] += __shfl_xor(partial[r], offl, 64);
        }
        if (l15 == 0) {
#pragma unroll
            for (int r = 0; r < 4; ++r) red[s & 1][w][4 * q + r] = partial[r];
        }
        __syncthreads();  // h(s), x(s+1), red(s) visible — ONE barrier per step
    }

    if (tid < 64) {  // final output, s = Ss-1
        const int ps = (Ss - 1) & 1;
        float v = red[ps][(tid >> 4) * 2][tid & 15] + red[ps][(tid >> 4) * 2 + 1][tid & 15] + bl0;
        outb[(size_t)(Ss - 1) * Hh + tid] = fsig(v);
    }
}

extern "C" void kernel_launch(void* const* d_in, const int* in_sizes, int n_in,
                              void* d_out, int out_size, void* d_ws, size_t ws_size,
                              hipStream_t stream) {
    const float* x  = (const float*)d_in[0];
    const float* Wc = (const float*)d_in[1];
    const float* bc = (const float*)d_in[2];
    const float* Wl = (const float*)d_in[3];
    const float* bl = (const float*)d_in[4];
    float* out = (float*)d_out;
    u16*   xT  = (u16*)d_ws;  // 64 MiB (proven available)

    dim3 tgrid(Tt * Cc / 128, Ss / 64, Bb);
    xpose_kernel<<<tgrid, 256, 0, stream>>>(x, xT);
    convlstm7_kernel<<<Bb, 512, 0, stream>>>(Wc, bc, Wl, bl, xT, out);
}

// Round 8
// 1408.575 us; speedup vs baseline: 3.4493x; 1.0522x over previous
//
#include <hip/hip_runtime.h>

// ConvLSTM on MI355X — round 8.
// r7 post-mortem: zpad was DCE'd (LDS stayed 55KB) -> occupancy theory untested.
// This round: round-1 structure (best measured, 1263us) + bias as register
// acc-init + LDS pad kept alive via runtime-opaque zkeep guard (store AND load
// -> not removable). Theory: LDS>80KB -> backend budgets 1 block/CU -> 256
// VGPRs/wave -> 144-reg weight set resident naturally (no pins, no remat).
// Only 32 blocks exist, so 1 block/CU is reality anyway - pad is free.

#define Bb 32
#define Tt 128
#define Cc 32
#define Ss 256
#define Hh 64
#define ZST 104  // Z row stride in u16 (208 B)

typedef __bf16 bf16x8 __attribute__((ext_vector_type(8)));
typedef short  short8 __attribute__((ext_vector_type(8)));
typedef float  f32x4  __attribute__((ext_vector_type(4)));
typedef unsigned short u16;
typedef unsigned int   u32;

__device__ __forceinline__ u16 f2bf(float f) {
    u32 u = __float_as_uint(f);
    u = (u + 0x7FFFu + ((u >> 16) & 1u)) >> 16;  // RNE
    return (u16)u;
}
__device__ __forceinline__ float fsig(float x) {
    float e = __expf(-x);
    return __builtin_amdgcn_rcpf(1.0f + e);
}
__device__ __forceinline__ float ftanh_(float x) {
    float e = __expf(2.0f * x);
    return 1.0f - 2.0f * __builtin_amdgcn_rcpf(e + 1.0f);
}

// ---------------- transpose: x (B,T,C,S) f32 -> xT (B,S,T*C) bf16 ----------------
__global__ __launch_bounds__(256) void xpose_kernel(const float* __restrict__ x,
                                                    u16* __restrict__ xT) {
    __shared__ u16 tile[64][130];
    const int tc0 = blockIdx.x * 128;
    const int s0  = blockIdx.y * 64;
    const int b   = blockIdx.z;
    const int tid = threadIdx.x;
    const float* xb = x + (size_t)b * (Tt * Cc * Ss);
#pragma unroll
    for (int i = 0; i < 32; ++i) {
        const int tcr = (tid >> 6) + 4 * i;
        const int sr  = tid & 63;
        tile[sr][tcr] = f2bf(xb[(size_t)(tc0 + tcr) * Ss + s0 + sr]);
    }
    __syncthreads();
    u32* xTo = (u32*)(xT + (size_t)b * (Ss * Tt * Cc));
#pragma unroll
    for (int j = 0; j < 16; ++j) {
        const int sw = (tid >> 6) + 4 * j;
        const int tw = (tid & 63) * 2;
        xTo[(((size_t)(s0 + sw)) * (Tt * Cc) + tc0 + tw) >> 1] = *(const u32*)&tile[sw][tw];
    }
}

// ---------------- recurrent kernel: one block per batch ----------------
__global__ __launch_bounds__(512) void convlstm8_kernel(
    const float* __restrict__ Wc, const float* __restrict__ bc,
    const float* __restrict__ Wl, const float* __restrict__ bl,
    const u16* __restrict__ xT, float* __restrict__ out, int zkeep) {

    // Z: rows 0..129 = t -1..128 (halo rows stay zero), cols 0..31 x, 32..95 h
    __shared__ u16  zbuf[2][130][ZST];
    __shared__ float red[8][16];
    // Occupancy shaping: push static LDS past 80 KiB so the backend's
    // LDS-derived occupancy is 1 block/CU -> register budget 256/wave.
    // Kept alive via zkeep (runtime 0, compiler can't prove it).
    __shared__ u16  zpad[14000];

    const int b    = blockIdx.x;
    const int tid  = threadIdx.x;
    const int w    = tid >> 6;     // wave 0..7
    const int lane = tid & 63;
    const int l15  = lane & 15;
    const int q    = lane >> 4;
    const int ht   = w >> 1;       // 16 h-rows tile
    const int th   = w & 1;        // t-half

    if (zkeep) {  // never true at runtime; forces zpad to stay allocated
        zpad[tid] = (u16)tid;
        out[tid & 63] += (float)zpad[(tid * 7) & 13999];
    }

    {   // zero both Z buffers (halos + h(-1) = 0)
        u32* z32 = (u32*)&zbuf[0][0][0];
        for (int i = tid; i < (2 * 130 * ZST) / 2; i += 512) z32[i] = 0;
    }

    // weight fragments, loop-invariant: afr[gate][tap][ks]; k-slot j -> ch 32*ks+8*q+j
    bf16x8 afr[4][3][3];
#pragma unroll
    for (int g = 0; g < 4; ++g)
#pragma unroll
        for (int k = 0; k < 3; ++k)
#pragma unroll
            for (int ks = 0; ks < 3; ++ks) {
                const int gc = 64 * g + 16 * ht + l15;
                short8 t;
#pragma unroll
                for (int j = 0; j < 8; ++j)
                    t[j] = (short)f2bf(Wc[gc * 288 + (32 * ks + 8 * q + j) * 3 + k]);
                afr[g][k][ks] = __builtin_bit_cast(bf16x8, t);
            }

    // bias (acc-init) and Wl
    f32x4 bcv[4];
#pragma unroll
    for (int g = 0; g < 4; ++g) bcv[g] = *(const f32x4*)&bc[64 * g + 16 * ht + 4 * q];
    float wlv[4];
#pragma unroll
    for (int nj = 0; nj < 4; ++nj) wlv[nj] = Wl[64 * th + 16 * nj + l15];
    const float bl0 = bl[0];

    float cst[16];
#pragma unroll
    for (int i = 0; i < 16; ++i) cst[i] = 0.0f;

    // x staging: thread -> (t = tid>>2, c0 = (tid&3)*8)
    const int xt = tid >> 2;
    const int xc = (tid & 3) * 8;
    const u16* xTb = xT + (size_t)b * (Ss * Tt * Cc);

    // prime x(0) into buffer 0
    {
        uint4 xv0 = *(const uint4*)(xTb + xt * 32 + xc);
        __syncthreads();  // zeroing complete
        *(uint4*)&zbuf[0][1 + xt][xc] = xv0;
        __syncthreads();  // x(0) visible
    }

    float* outb = out + (size_t)b * (Ss * Hh);
    int p = 0;

    for (int s = 0; s < Ss; ++s) {
        // prefetch x(s+1)
        uint4 xv;
        const bool havex = (s + 1) < Ss;
        if (havex) xv = *(const uint4*)(xTb + (size_t)(s + 1) * (Tt * Cc) + xt * 32 + xc);

        // emit output for step s-1
        if (tid < 64 && s > 0) {
            float v = red[(tid >> 4) * 2][tid & 15] + red[(tid >> 4) * 2 + 1][tid & 15] + bl0;
            outb[(size_t)(s - 1) * Hh + tid] = fsig(v);
        }
        __syncthreads();  // barrier A: red consumed before rewrite

        const u16 (*zb)[ZST] = zbuf[p];
        u16 (*zn)[ZST] = zbuf[p ^ 1];

        float partial[4] = {0.f, 0.f, 0.f, 0.f};

#pragma unroll
        for (int half = 0; half < 2; ++half) {
            f32x4 acc[4][2];
#pragma unroll
            for (int g = 0; g < 4; ++g) {
                acc[g][0] = bcv[g];
                acc[g][1] = bcv[g];
            }
#pragma unroll
            for (int njl = 0; njl < 2; ++njl) {
                const int nj = half * 2 + njl;
                const int tb = 64 * th + 16 * nj + l15;
#pragma unroll
                for (int k = 0; k < 3; ++k)
#pragma unroll
                    for (int ks = 0; ks < 3; ++ks) {
                        bf16x8 bfr = *(const bf16x8*)&zb[tb + k][32 * ks + 8 * q];
                        acc[0][njl] = __builtin_amdgcn_mfma_f32_16x16x32_bf16(afr[0][k][ks], bfr, acc[0][njl], 0, 0, 0);
                        acc[1][njl] = __builtin_amdgcn_mfma_f32_16x16x32_bf16(afr[1][k][ks], bfr, acc[1][njl], 0, 0, 0);
                        acc[2][njl] = __builtin_amdgcn_mfma_f32_16x16x32_bf16(afr[2][k][ks], bfr, acc[2][njl], 0, 0, 0);
                        acc[3][njl] = __builtin_amdgcn_mfma_f32_16x16x32_bf16(afr[3][k][ks], bfr, acc[3][njl], 0, 0, 0);
                    }
            }

#pragma unroll
            for (int njl = 0; njl < 2; ++njl) {
                const int nj = half * 2 + njl;
                u16 hp[4];
#pragma unroll
                for (int r = 0; r < 4; ++r) {
                    const float ig = fsig(acc[0][njl][r]);
                    const float fg = fsig(acc[1][njl][r]);
                    const float og = fsig(acc[2][njl][r]);
                    const float gg = ftanh_(acc[3][njl][r]);
                    const float cv = fg * cst[nj * 4 + r] + ig * gg;
                    cst[nj * 4 + r] = cv;
                    const float hv = og * ftanh_(cv);
                    partial[r] += hv * wlv[nj];
                    hp[r] = f2bf(hv);
                }
                uint2 hw;
                hw.x = (u32)hp[0] | ((u32)hp[1] << 16);
                hw.y = (u32)hp[2] | ((u32)hp[3] << 16);
                *(uint2*)&zn[1 + 64 * th + 16 * nj + l15][32 + 16 * ht + 4 * q] = hw;
            }
        }

        // write prefetched x(s+1)
        if (havex) *(uint4*)&zn[1 + xt][xc] = xv;

        // reduce output partials over the 16 t-lanes of each quarter
#pragma unroll
        for (int r = 0; r < 4; ++r) {
#pragma unroll
            for (int offl = 1; offl <= 8; offl <<= 1)
                partial[r] += __shfl_xor(partial[r], offl, 64);
        }
        if (l15 == 0) {
#pragma unroll
            for (int r = 0; r < 4; ++r) red[w][4 * q + r] = partial[r];
        }
        __syncthreads();  // barrier B: h(s), x(s+1), red visible
        p ^= 1;
    }

    if (tid < 64) {  // final output, s = Ss-1
        float v = red[(tid >> 4) * 2][tid & 15] + red[(tid >> 4) * 2 + 1][tid & 15] + bl0;
        outb[(size_t)(Ss - 1) * Hh + tid] = fsig(v);
    }
}

extern "C" void kernel_launch(void* const* d_in, const int* in_sizes, int n_in,
                              void* d_out, int out_size, void* d_ws, size_t ws_size,
                              hipStream_t stream) {
    const float* x  = (const float*)d_in[0];
    const float* Wc = (const float*)d_in[1];
    const float* bc = (const float*)d_in[2];
    const float* Wl = (const float*)d_in[3];
    const float* bl = (const float*)d_in[4];
    float* out = (float*)d_out;
    u16*   xT  = (u16*)d_ws;  // 64 MiB (proven available)

    dim3 tgrid(Tt * Cc / 128, Ss / 64, Bb);
    xpose_kernel<<<tgrid, 256, 0, stream>>>(x, xT);
    convlstm8_kernel<<<Bb, 512, 0, stream>>>(Wc, bc, Wl, bl, xT, out, 0);
}

// Round 9
// 1327.274 us; speedup vs baseline: 3.6606x; 1.0613x over previous
//
#include <hip/hip_runtime.h>

// ConvLSTM on MI355X — round 9.
// r8 post-mortem: LDS-pad landed (82944) and VGPR stayed 128 -> occupancy-budget
// theory dead; bias-in-regs spilled (WRITE_SIZE +1.4MB, +146us) -> revert to r1's
// bcl scheme. New lever: r1's two waves per SIMD run identical phase sequences in
// lockstep -> VALU phase and MFMA phase serialize (time=sum). The two nj-halves
// are fully independent (disjoint cst, disjoint h rows), so wave group A (w<4)
// runs half0->half1 and group B (w>=4) runs half1->half0: SIMD partners (w,w+4)
// sit in OPPOSITE phases -> gate VALU overlaps partner's MFMAs. Zero new
// registers, zero new LDS, bit-identical math per wave. Plus s_setprio(1)
// around the MFMA cluster (T5: role diversity now exists).

#define Bb 32
#define Tt 128
#define Cc 32
#define Ss 256
#define Hh 64
#define ZST 104  // Z row stride in u16 (208 B)

typedef __bf16 bf16x8 __attribute__((ext_vector_type(8)));
typedef short  short8 __attribute__((ext_vector_type(8)));
typedef float  f32x4  __attribute__((ext_vector_type(4)));
typedef unsigned short u16;
typedef unsigned int   u32;

__device__ __forceinline__ u16 f2bf(float f) {
    u32 u = __float_as_uint(f);
    u = (u + 0x7FFFu + ((u >> 16) & 1u)) >> 16;  // RNE
    return (u16)u;
}
__device__ __forceinline__ float fsig(float x) {
    float e = __expf(-x);
    return __builtin_amdgcn_rcpf(1.0f + e);
}
__device__ __forceinline__ float ftanh_(float x) {
    float e = __expf(2.0f * x);
    return 1.0f - 2.0f * __builtin_amdgcn_rcpf(e + 1.0f);
}

// ---------------- transpose: x (B,T,C,S) f32 -> xT (B,S,T*C) bf16 ----------------
__global__ __launch_bounds__(256) void xpose_kernel(const float* __restrict__ x,
                                                    u16* __restrict__ xT) {
    __shared__ u16 tile[64][130];
    const int tc0 = blockIdx.x * 128;
    const int s0  = blockIdx.y * 64;
    const int b   = blockIdx.z;
    const int tid = threadIdx.x;
    const float* xb = x + (size_t)b * (Tt * Cc * Ss);
#pragma unroll
    for (int i = 0; i < 32; ++i) {
        const int tcr = (tid >> 6) + 4 * i;
        const int sr  = tid & 63;
        tile[sr][tcr] = f2bf(xb[(size_t)(tc0 + tcr) * Ss + s0 + sr]);
    }
    __syncthreads();
    u32* xTo = (u32*)(xT + (size_t)b * (Ss * Tt * Cc));
#pragma unroll
    for (int j = 0; j < 16; ++j) {
        const int sw = (tid >> 6) + 4 * j;
        const int tw = (tid & 63) * 2;
        xTo[(((size_t)(s0 + sw)) * (Tt * Cc) + tc0 + tw) >> 1] = *(const u32*)&tile[sw][tw];
    }
}

// ---------------- recurrent kernel: one block per batch ----------------
__global__ __launch_bounds__(512, 2) void convlstm9_kernel(
    const float* __restrict__ Wc, const float* __restrict__ bc,
    const float* __restrict__ Wl, const float* __restrict__ bl,
    const u16* __restrict__ xT, float* __restrict__ out) {

    // Z: rows 0..129 = t -1..128 (halo rows stay zero), cols 0..31 x, 32..95 h
    __shared__ u16  zbuf[2][130][ZST];
    __shared__ float red[8][16];
    __shared__ float bcl[256];

    const int b    = blockIdx.x;
    const int tid  = threadIdx.x;
    const int w    = tid >> 6;     // wave 0..7
    const int lane = tid & 63;
    const int l15  = lane & 15;
    const int q    = lane >> 4;
    const int ht   = w >> 1;       // 16 h-rows tile
    const int th   = w & 1;        // t-half
    const int grp  = w >> 2;       // anti-phase group: SIMD partners (w, w+4) differ

    {   // zero both Z buffers (halos + h(-1) = 0)
        u32* z32 = (u32*)&zbuf[0][0][0];
        for (int i = tid; i < (2 * 130 * ZST) / 2; i += 512) z32[i] = 0;
    }
    if (tid < 256) bcl[tid] = bc[tid];

    // weight fragments: afr[gate][tap][ks]; k-slot j -> ch 32*ks+8*q+j
    bf16x8 afr[4][3][3];
#pragma unroll
    for (int g = 0; g < 4; ++g)
#pragma unroll
        for (int k = 0; k < 3; ++k)
#pragma unroll
            for (int ks = 0; ks < 3; ++ks) {
                const int gc = 64 * g + 16 * ht + l15;
                short8 t;
#pragma unroll
                for (int j = 0; j < 8; ++j)
                    t[j] = (short)f2bf(Wc[gc * 288 + (32 * ks + 8 * q + j) * 3 + k]);
                afr[g][k][ks] = __builtin_bit_cast(bf16x8, t);
            }

    float wlv[4];
#pragma unroll
    for (int nj = 0; nj < 4; ++nj) wlv[nj] = Wl[64 * th + 16 * nj + l15];
    const float bl0 = bl[0];

    float cst[16];
#pragma unroll
    for (int i = 0; i < 16; ++i) cst[i] = 0.0f;

    // x staging: thread -> (t = tid>>2, c0 = (tid&3)*8)
    const int xt = tid >> 2;
    const int xc = (tid & 3) * 8;
    const u16* xTb = xT + (size_t)b * (Ss * Tt * Cc);

    // prime x(0) into buffer 0
    {
        uint4 xv0 = *(const uint4*)(xTb + xt * 32 + xc);
        __syncthreads();  // zeroing + bcl complete
        *(uint4*)&zbuf[0][1 + xt][xc] = xv0;
        __syncthreads();  // x(0) visible
    }

    float* outb = out + (size_t)b * (Ss * Hh);
    int p = 0;

    for (int s = 0; s < Ss; ++s) {
        // prefetch x(s+1)
        uint4 xv;
        const bool havex = (s + 1) < Ss;
        if (havex) xv = *(const uint4*)(xTb + (size_t)(s + 1) * (Tt * Cc) + xt * 32 + xc);

        // emit output for step s-1
        if (tid < 64 && s > 0) {
            float v = red[(tid >> 4) * 2][tid & 15] + red[(tid >> 4) * 2 + 1][tid & 15] + bl0;
            outb[(size_t)(s - 1) * Hh + tid] = fsig(v);
        }
        __syncthreads();  // barrier A: red consumed before rewrite

        const u16 (*zb)[ZST] = zbuf[p];
        u16 (*zn)[ZST] = zbuf[p ^ 1];

        float partial[4] = {0.f, 0.f, 0.f, 0.f};

#pragma unroll
        for (int hh = 0; hh < 2; ++hh) {
            const int half = hh ^ grp;   // group 0: 0,1 ; group 1: 1,0 (anti-phase)

            f32x4 acc[4][2];
#pragma unroll
            for (int g = 0; g < 4; ++g) {
                acc[g][0] = (f32x4){0.f, 0.f, 0.f, 0.f};
                acc[g][1] = (f32x4){0.f, 0.f, 0.f, 0.f};
            }

            __builtin_amdgcn_s_setprio(1);
#pragma unroll
            for (int njl = 0; njl < 2; ++njl) {
                const int nj = half * 2 + njl;
                const int tb = 64 * th + 16 * nj + l15;
#pragma unroll
                for (int k = 0; k < 3; ++k)
#pragma unroll
                    for (int ks = 0; ks < 3; ++ks) {
                        bf16x8 bfr = *(const bf16x8*)&zb[tb + k][32 * ks + 8 * q];
                        acc[0][njl] = __builtin_amdgcn_mfma_f32_16x16x32_bf16(afr[0][k][ks], bfr, acc[0][njl], 0, 0, 0);
                        acc[1][njl] = __builtin_amdgcn_mfma_f32_16x16x32_bf16(afr[1][k][ks], bfr, acc[1][njl], 0, 0, 0);
                        acc[2][njl] = __builtin_amdgcn_mfma_f32_16x16x32_bf16(afr[2][k][ks], bfr, acc[2][njl], 0, 0, 0);
                        acc[3][njl] = __builtin_amdgcn_mfma_f32_16x16x32_bf16(afr[3][k][ks], bfr, acc[3][njl], 0, 0, 0);
                    }
            }
            __builtin_amdgcn_s_setprio(0);

#pragma unroll
            for (int njl = 0; njl < 2; ++njl) {
                const int nj = half * 2 + njl;
                u16 hp[4];
#pragma unroll
                for (int r = 0; r < 4; ++r) {
                    const int hl = 4 * q + r;
                    const float ig = fsig(acc[0][njl][r] + bcl[0   + 16 * ht + hl]);
                    const float fg = fsig(acc[1][njl][r] + bcl[64  + 16 * ht + hl]);
                    const float og = fsig(acc[2][njl][r] + bcl[128 + 16 * ht + hl]);
                    const float gg = ftanh_(acc[3][njl][r] + bcl[192 + 16 * ht + hl]);
                    const float cv = fg * cst[nj * 4 + r] + ig * gg;
                    cst[nj * 4 + r] = cv;
                    const float hv = og * ftanh_(cv);
                    partial[r] += hv * wlv[nj];
                    hp[r] = f2bf(hv);
                }
                uint2 hw;
                hw.x = (u32)hp[0] | ((u32)hp[1] << 16);
                hw.y = (u32)hp[2] | ((u32)hp[3] << 16);
                *(uint2*)&zn[1 + 64 * th + 16 * nj + l15][32 + 16 * ht + 4 * q] = hw;
            }
        }

        // write prefetched x(s+1)
        if (havex) *(uint4*)&zn[1 + xt][xc] = xv;

        // reduce output partials over the 16 t-lanes of each quarter
#pragma unroll
        for (int r = 0; r < 4; ++r) {
#pragma unroll
            for (int offl = 1; offl <= 8; offl <<= 1)
                partial[r] += __shfl_xor(partial[r], offl, 64);
        }
        if (l15 == 0) {
#pragma unroll
            for (int r = 0; r < 4; ++r) red[w][4 * q + r] = partial[r];
        }
        __syncthreads();  // barrier B: h(s), x(s+1), red visible
        p ^= 1;
    }

    if (tid < 64) {  // final output, s = Ss-1
        float v = red[(tid >> 4) * 2][tid & 15] + red[(tid >> 4) * 2 + 1][tid & 15] + bl0;
        outb[(size_t)(Ss - 1) * Hh + tid] = fsig(v);
    }
}

extern "C" void kernel_launch(void* const* d_in, const int* in_sizes, int n_in,
                              void* d_out, int out_size, void* d_ws, size_t ws_size,
                              hipStream_t stream) {
    const float* x  = (const float*)d_in[0];
    const float* Wc = (const float*)d_in[1];
    const float* bc = (const float*)d_in[2];
    const float* Wl = (const float*)d_in[3];
    const float* bl = (const float*)d_in[4];
    float* out = (float*)d_out;
    u16*   xT  = (u16*)d_ws;  // 64 MiB (proven available)

    dim3 tgrid(Tt * Cc / 128, Ss / 64, Bb);
    xpose_kernel<<<tgrid, 256, 0, stream>>>(x, xT);
    convlstm9_kernel<<<Bb, 512, 0, stream>>>(Wc, bc, Wl, bl, xT, out);
}